// Round 4
// baseline (204.246 us; speedup 1.0000x reference)
//
#include <hip/hip_runtime.h>
#include <hip/hip_fp16.h>
#include <string.h>

namespace {
constexpr int kN = 50000;
constexpr int kD = 256;
constexpr int kPos = 32;
constexpr int kNeg = 20;
constexpr float kEps = 1e-15f;
constexpr int kSlots = kPos / 4 + kNeg / 4;  // 13 per 16-lane group

typedef float floatx2 __attribute__((ext_vector_type(2)));

#if __has_builtin(__builtin_amdgcn_cvt_pk_f32_fp8)
constexpr bool kHwCvtPk = true;
constexpr bool kHwCvt1 = false;
#elif __has_builtin(__builtin_amdgcn_cvt_f32_fp8)
constexpr bool kHwCvtPk = false;
constexpr bool kHwCvt1 = true;
#else
constexpr bool kHwCvtPk = false;
constexpr bool kHwCvt1 = false;
#endif
// software-decode fallback yields value*2^-8, so own must be pre-scaled by 256
constexpr float kOwnScale = (kHwCvtPk || kHwCvt1) ? 1.f : 256.f;

// ---------- software fp8 e4m3fn <-> f32 via the f16 bit-correspondence ----------
// ENCODE IS UNCHANGED: table bytes are bit-identical to the verified kernel.
__device__ __forceinline__ uint enc1(float x) {
    const __half hh = __float2half(x * 0.00390625f);  // x * 2^-8, HW RNE
    unsigned short t;
    memcpy(&t, &hh, 2);
    const uint s = ((uint)t >> 8) & 0x80u;
    uint mag = (uint)t & 0x7fffu;
    mag = mag + 0x3fu + ((mag >> 7) & 1u);  // RNE 10->3 bit mantissa
    uint u = mag >> 7;
    if (u > 0x7eu) u = 0x7eu;
    return s | u;
}

__device__ __forceinline__ float dec_h(uint h) {
    __half hh;
    const unsigned short t = (unsigned short)h;
    memcpy(&hh, &t, 2);
    return __half2float(hh);
}

// Decode 4 packed e4m3 bytes, accumulate dot with o.x..o.w into d.
__device__ __forceinline__ void dq4f(uint u, const float4& o, float& d) {
#if __has_builtin(__builtin_amdgcn_cvt_pk_f32_fp8)
    const floatx2 lo = __builtin_amdgcn_cvt_pk_f32_fp8((int)u, false);  // bytes 0,1
    const floatx2 hi = __builtin_amdgcn_cvt_pk_f32_fp8((int)u, true);   // bytes 2,3
    d = fmaf(lo.x, o.x, d);
    d = fmaf(lo.y, o.y, d);
    d = fmaf(hi.x, o.z, d);
    d = fmaf(hi.y, o.w, d);
#elif __has_builtin(__builtin_amdgcn_cvt_f32_fp8)
    d = fmaf(__builtin_amdgcn_cvt_f32_fp8((int)u, 0), o.x, d);
    d = fmaf(__builtin_amdgcn_cvt_f32_fp8((int)u, 1), o.y, d);
    d = fmaf(__builtin_amdgcn_cvt_f32_fp8((int)u, 2), o.z, d);
    d = fmaf(__builtin_amdgcn_cvt_f32_fp8((int)u, 3), o.w, d);
#else
    const float v0 = dec_h(((u << 8) & 0x8000u) | ((u << 7) & 0x3f80u));
    const float v1 = dec_h((u & 0x8000u) | ((u >> 1) & 0x3f80u));
    const float v2 = dec_h(((u >> 8) & 0x8000u) | ((u >> 9) & 0x3f80u));
    const float v3 = dec_h(((u >> 16) & 0x8000u) | ((u >> 17) & 0x3f80u));
    d = fmaf(v0, o.x, d);
    d = fmaf(v1, o.y, d);
    d = fmaf(v2, o.z, d);
    d = fmaf(v3, o.w, d);
#endif
}

// ---------- fp32 -> fp8 table; 8 elems/thread (UNCHANGED) ----------
__global__ __launch_bounds__(256) void convert_fp8(const float* __restrict__ emb,
                                                   uint* __restrict__ tbl) {
    const size_t i = ((size_t)blockIdx.x * 256 + threadIdx.x) * 8;
    const float4* src = reinterpret_cast<const float4*>(emb + i);
    const float4 a = src[0];
    const float4 b = src[1];
    uint2 o;
    o.x = enc1(a.x) | (enc1(a.y) << 8) | (enc1(a.z) << 16) | (enc1(a.w) << 24);
    o.y = enc1(b.x) | (enc1(b.y) << 8) | (enc1(b.z) << 16) | (enc1(b.w) << 24);
    reinterpret_cast<uint2*>(tbl)[i / 8] = o;
}

// ---------- active-row compaction (order irrelevant) ----------
__global__ __launch_bounds__(256) void compact_kernel(const int* __restrict__ rmask,
                                                      int* __restrict__ list,
                                                      float* __restrict__ acc) {
    const int n = blockIdx.x * 256 + threadIdx.x;
    if (n < kN && rmask[n]) {
        const int p = atomicAdd(reinterpret_cast<unsigned*>(&acc[2]), 1u);
        list[p] = n;
    }
}

// One wave per ACTIVE row; wave = 4 groups x 16 lanes, one neighbor per group
// per slot, 13 slots, branch-free.
// D-SLICED EPOCHS: the dot products run in 4 epochs over D; epoch q reads only
// bytes [64q,64q+64) of every gathered row (lane t loads one dword at
// idx*256 + 64q + 4t; per-slot partials live in dlane[13] registers, reduced
// once after the last epoch). All resident waves progress through epochs
// roughly together, so the live gather working set is ~3.2 MB -> fits each
// XCD's 4 MiB L2 (vs 12.8 MB random). Per-wave line count unchanged
// (13 slots x 4 epochs x one 64B line per 16-lane group = 52 lines).
__global__ __launch_bounds__(256) void row_loss_fp8(
    const float* __restrict__ emb,
    const uchar* __restrict__ tblb,
    const int* __restrict__ nbr,
    const int* __restrict__ nbrm,
    const int* __restrict__ neg,
    const int* __restrict__ list,
    float* __restrict__ acc) {
    __shared__ float s_num[4];
    const int wave = threadIdx.x >> 6;
    const int lane = threadIdx.x & 63;
    const int g = lane >> 4;
    const int t = lane & 15;

    const int cnt_active = reinterpret_cast<const int*>(acc)[2];
    const int i = blockIdx.x * 4 + wave;
    float num = 0.f;

    if (i < cnt_active) {  // wave-uniform
        const int n = list[i];

        // own row fp32 (exact): epoch q needs elems 64q+4t .. 64q+4t+3
        const float4* erow = reinterpret_cast<const float4*>(emb + (size_t)n * kD);
        float4 own4[4];
#pragma unroll
        for (int q = 0; q < 4; ++q) {
            const float4 f = erow[16 * q + t];
            own4[q].x = f.x * kOwnScale;
            own4[q].y = f.y * kOwnScale;
            own4[q].z = f.z * kOwnScale;
            own4[q].w = f.w * kOwnScale;
        }

        const int* nrow = nbr + (size_t)n * kPos;
        const int* mrow = nbrm + (size_t)n * kPos;
        const int* grow = neg + (size_t)n * kNeg;

        uint offb[kSlots];  // row base byte offsets (idx*256)
        float w[kPos / 4];
        float cnt = 0.f;
#pragma unroll
        for (int s = 0; s < kPos / 4; ++s) {
            offb[s] = (uint)nrow[s * 4 + g] << 8;
            const float mf = (float)mrow[s * 4 + g];
            w[s] = mf;
            cnt += mf;
        }
#pragma unroll
        for (int s = 0; s < kNeg / 4; ++s)
            offb[kPos / 4 + s] = (uint)grow[s * 4 + g] << 8;

        float dlane[kSlots];
#pragma unroll
        for (int s = 0; s < kSlots; ++s) dlane[s] = 0.f;

        const uchar* tbl_t = tblb + 4u * (uint)t;  // lane's dword within the slice
#pragma unroll
        for (int q = 0; q < 4; ++q) {
            uint u[kSlots];
#pragma unroll
            for (int s = 0; s < kSlots; ++s)
                u[s] = *reinterpret_cast<const uint*>(tbl_t + offb[s] + 64u * (uint)q);
#pragma unroll
            for (int s = 0; s < kSlots; ++s) dq4f(u[s], own4[q], dlane[s]);
        }

        float pos_sum = 0.f, neg_sum = 0.f;
#pragma unroll
        for (int s = 0; s < kSlots; ++s) {
            float d = dlane[s];
            d += __shfl_xor(d, 8);
            d += __shfl_xor(d, 4);
            d += __shfl_xor(d, 2);
            d += __shfl_xor(d, 1);
            const float sg = 1.f / (1.f + __expf(-d));
            if (s < kPos / 4) {  // compile-time branch (fully unrolled)
                pos_sum += -__logf(sg + kEps) * w[s];
            } else {
                neg_sum += -__logf(1.f - sg + kEps);
            }
        }

        // combine the 4 groups (each group's 16 lanes hold identical values)
        pos_sum += __shfl_xor(pos_sum, 16);
        pos_sum += __shfl_xor(pos_sum, 32);
        neg_sum += __shfl_xor(neg_sum, 16);
        neg_sum += __shfl_xor(neg_sum, 32);
        cnt += __shfl_xor(cnt, 16);
        cnt += __shfl_xor(cnt, 32);

        if (cnt > 0.f) num = pos_sum / cnt + neg_sum / (float)kNeg;
        // cnt==0 -> NaN row in reference -> replaced by 0 -> contributes 0
    }

    if (lane == 0) s_num[wave] = num;
    __syncthreads();
    if (threadIdx.x == 0) {
        const float v = s_num[0] + s_num[1] + s_num[2] + s_num[3];
        if (v != 0.f) atomicAdd(&acc[0], v);
    }
}

__global__ void finalize_kernel(const float* __restrict__ acc, float* __restrict__ out) {
    out[0] = acc[0] / (float)reinterpret_cast<const int*>(acc)[2];
}

// ---------- fp32 direct fallback (only if d_ws too small; UNCHANGED) ----------
__global__ __launch_bounds__(256) void row_loss_f32(
    const float* __restrict__ emb,
    const int* __restrict__ nbr,
    const int* __restrict__ nbrm,
    const int* __restrict__ neg,
    const int* __restrict__ rmask,
    float* __restrict__ acc) {
    __shared__ float s_num[4];
    __shared__ float s_den[4];
    const int wave = threadIdx.x >> 6;
    const int lane = threadIdx.x & 63;
    const int n = blockIdx.x * 4 + wave;
    const int g = lane >> 4;
    const int t = lane & 15;

    const float4* erow = reinterpret_cast<const float4*>(emb + (size_t)n * kD);
    float4 own4[4];
#pragma unroll
    for (int j = 0; j < 4; ++j) own4[j] = erow[j * 16 + t];

    const int* nrow = nbr + (size_t)n * kPos;
    const int* mrow = nbrm + (size_t)n * kPos;
    const int* grow = neg + (size_t)n * kNeg;

    float pos_sum = 0.f, neg_sum = 0.f, cnt = 0.f;
#pragma unroll
    for (int it = 0; it < kPos / 4; ++it) {
        const int idx = nrow[it * 4 + g];
        const float mf = (float)mrow[it * 4 + g];
        cnt += mf;
        const float4* brow = reinterpret_cast<const float4*>(emb + (size_t)idx * kD);
        float d = 0.f;
#pragma unroll
        for (int j = 0; j < 4; ++j) {
            const float4 b = brow[j * 16 + t];
            const float4 a = own4[j];
            d += a.x * b.x + a.y * b.y + a.z * b.z + a.w * b.w;
        }
        d += __shfl_xor(d, 8);
        d += __shfl_xor(d, 4);
        d += __shfl_xor(d, 2);
        d += __shfl_xor(d, 1);
        const float s = 1.f / (1.f + __expf(-d));
        pos_sum += -__logf(s + kEps) * mf;
    }
#pragma unroll
    for (int it = 0; it < kNeg / 4; ++it) {
        const int idx = grow[it * 4 + g];
        const float4* brow = reinterpret_cast<const float4*>(emb + (size_t)idx * kD);
        float d = 0.f;
#pragma unroll
        for (int j = 0; j < 4; ++j) {
            const float4 b = brow[j * 16 + t];
            const float4 a = own4[j];
            d += a.x * b.x + a.y * b.y + a.z * b.z + a.w * b.w;
        }
        d += __shfl_xor(d, 8);
        d += __shfl_xor(d, 4);
        d += __shfl_xor(d, 2);
        d += __shfl_xor(d, 1);
        const float s = 1.f / (1.f + __expf(-d));
        neg_sum += -__logf(1.f - s + kEps);
    }

    pos_sum += __shfl_xor(pos_sum, 16);
    pos_sum += __shfl_xor(pos_sum, 32);
    neg_sum += __shfl_xor(neg_sum, 16);
    neg_sum += __shfl_xor(neg_sum, 32);
    cnt += __shfl_xor(cnt, 16);
    cnt += __shfl_xor(cnt, 32);

    float num = 0.f;
    if (cnt > 0.f) num = pos_sum / cnt + neg_sum / (float)kNeg;
    const float rmf = (float)rmask[n];

    if (lane == 0) {
        s_num[wave] = num * rmf;
        s_den[wave] = rmf;
    }
    __syncthreads();
    if (threadIdx.x == 0) {
        atomicAdd(&acc[0], s_num[0] + s_num[1] + s_num[2] + s_num[3]);
        atomicAdd(&acc[1], s_den[0] + s_den[1] + s_den[2] + s_den[3]);
    }
}

__global__ void finalize_f32(const float* __restrict__ acc, float* __restrict__ out) {
    out[0] = acc[0] / acc[1];
}
}  // namespace

extern "C" void kernel_launch(void* const* d_in, const int* in_sizes, int n_in,
                              void* d_out, int out_size, void* d_ws, size_t ws_size,
                              hipStream_t stream) {
    const float* emb = (const float*)d_in[0];
    const int* nbr = (const int*)d_in[1];
    const int* nbrm = (const int*)d_in[2];
    const int* neg = (const int*)d_in[3];
    const int* rmask = (const int*)d_in[4];
    float* acc = (float*)d_ws;  // [0]=num, [1]=den, [2]=active count

    const size_t tbl_bytes = (size_t)kN * kD;  // 12.8 MB
    const size_t list_bytes = (size_t)kN * sizeof(int);
    if (ws_size >= 256 + tbl_bytes + list_bytes) {
        uint* tbl = (uint*)((char*)d_ws + 256);
        int* list = (int*)((char*)d_ws + 256 + tbl_bytes);
        hipMemsetAsync(acc, 0, 4 * sizeof(float), stream);
        compact_kernel<<<(kN + 255) / 256, 256, 0, stream>>>(rmask, list, acc);
        convert_fp8<<<kN * kD / 8 / 256, 256, 0, stream>>>(emb, tbl);
        row_loss_fp8<<<(kN + 3) / 4, 256, 0, stream>>>(emb, (const uchar*)tbl, nbr,
                                                       nbrm, neg, list, acc);
        finalize_kernel<<<1, 1, 0, stream>>>(acc, (float*)d_out);
    } else {
        hipMemsetAsync(acc, 0, 2 * sizeof(float), stream);
        row_loss_f32<<<kN / 4, 256, 0, stream>>>(emb, nbr, nbrm, neg, rmask, acc);
        finalize_f32<<<1, 1, 0, stream>>>(acc, (float*)d_out);
    }
}

// Round 5
// 202.749 us; speedup vs baseline: 1.0074x; 1.0074x over previous
//
#include <hip/hip_runtime.h>
#include <hip/hip_fp16.h>
#include <string.h>

namespace {
constexpr int kN = 50000;
constexpr int kD = 256;
constexpr int kPos = 32;
constexpr int kNeg = 20;
constexpr float kEps = 1e-15f;
constexpr int kSlots = kPos / 4 + kNeg / 4;  // 13 per 16-lane group

typedef float floatx2 __attribute__((ext_vector_type(2)));
typedef uint uintx4 __attribute__((ext_vector_type(4)));

#if __has_builtin(__builtin_amdgcn_cvt_pk_f32_fp8)
constexpr bool kHwCvtPk = true;
constexpr bool kHwCvt1 = false;
#elif __has_builtin(__builtin_amdgcn_cvt_f32_fp8)
constexpr bool kHwCvtPk = false;
constexpr bool kHwCvt1 = true;
#else
constexpr bool kHwCvtPk = false;
constexpr bool kHwCvt1 = false;
#endif
// software-decode fallback yields value*2^-8, so own must be pre-scaled by 256
constexpr float kOwnScale = (kHwCvtPk || kHwCvt1) ? 1.f : 256.f;

// ---------- software fp8 e4m3fn <-> f32 via the f16 bit-correspondence ----------
// ENCODE IS UNCHANGED: table bytes are bit-identical to the verified kernel.
__device__ __forceinline__ uint enc1(float x) {
    const __half hh = __float2half(x * 0.00390625f);  // x * 2^-8, HW RNE
    unsigned short t;
    memcpy(&t, &hh, 2);
    const uint s = ((uint)t >> 8) & 0x80u;
    uint mag = (uint)t & 0x7fffu;
    mag = mag + 0x3fu + ((mag >> 7) & 1u);  // RNE 10->3 bit mantissa
    uint u = mag >> 7;
    if (u > 0x7eu) u = 0x7eu;
    return s | u;
}

__device__ __forceinline__ float dec_h(uint h) {
    __half hh;
    const unsigned short t = (unsigned short)h;
    memcpy(&hh, &t, 2);
    return __half2float(hh);
}

// Decode 4 packed e4m3 bytes, accumulate dot with o.x..o.w into d.
__device__ __forceinline__ void dq4f(uint u, const float4& o, float& d) {
#if __has_builtin(__builtin_amdgcn_cvt_pk_f32_fp8)
    const floatx2 lo = __builtin_amdgcn_cvt_pk_f32_fp8((int)u, false);  // bytes 0,1
    const floatx2 hi = __builtin_amdgcn_cvt_pk_f32_fp8((int)u, true);   // bytes 2,3
    d = fmaf(lo.x, o.x, d);
    d = fmaf(lo.y, o.y, d);
    d = fmaf(hi.x, o.z, d);
    d = fmaf(hi.y, o.w, d);
#elif __has_builtin(__builtin_amdgcn_cvt_f32_fp8)
    d = fmaf(__builtin_amdgcn_cvt_f32_fp8((int)u, 0), o.x, d);
    d = fmaf(__builtin_amdgcn_cvt_f32_fp8((int)u, 1), o.y, d);
    d = fmaf(__builtin_amdgcn_cvt_f32_fp8((int)u, 2), o.z, d);
    d = fmaf(__builtin_amdgcn_cvt_f32_fp8((int)u, 3), o.w, d);
#else
    const float v0 = dec_h(((u << 8) & 0x8000u) | ((u << 7) & 0x3f80u));
    const float v1 = dec_h((u & 0x8000u) | ((u >> 1) & 0x3f80u));
    const float v2 = dec_h(((u >> 8) & 0x8000u) | ((u >> 9) & 0x3f80u));
    const float v3 = dec_h(((u >> 16) & 0x8000u) | ((u >> 17) & 0x3f80u));
    d = fmaf(v0, o.x, d);
    d = fmaf(v1, o.y, d);
    d = fmaf(v2, o.z, d);
    d = fmaf(v3, o.w, d);
#endif
}

// dot over this lane's 16 elems + 16-lane-group reduce (same op order as the
// verified round-1 kernel -> bit-identical result).
__device__ __forceinline__ float dot16(const uintx4 u, const float4* o) {
    float d = 0.f;
    dq4f(u[0], o[0], d);
    dq4f(u[1], o[1], d);
    dq4f(u[2], o[2], d);
    dq4f(u[3], o[3], d);
    d += __shfl_xor(d, 8);
    d += __shfl_xor(d, 4);
    d += __shfl_xor(d, 2);
    d += __shfl_xor(d, 1);
    return d;
}

// ---------- fp32 -> fp8 table; 8 elems/thread (UNCHANGED) ----------
__global__ __launch_bounds__(256) void convert_fp8(const float* __restrict__ emb,
                                                   uint* __restrict__ tbl) {
    const size_t i = ((size_t)blockIdx.x * 256 + threadIdx.x) * 8;
    const float4* src = reinterpret_cast<const float4*>(emb + i);
    const float4 a = src[0];
    const float4 b = src[1];
    uint2 o;
    o.x = enc1(a.x) | (enc1(a.y) << 8) | (enc1(a.z) << 16) | (enc1(a.w) << 24);
    o.y = enc1(b.x) | (enc1(b.y) << 8) | (enc1(b.z) << 16) | (enc1(b.w) << 24);
    reinterpret_cast<uint2*>(tbl)[i / 8] = o;
}

// ---------- active-row compaction (order irrelevant) ----------
__global__ __launch_bounds__(256) void compact_kernel(const int* __restrict__ rmask,
                                                      int* __restrict__ list,
                                                      float* __restrict__ acc) {
    const int n = blockIdx.x * 256 + threadIdx.x;
    if (n < kN && rmask[n]) {
        const int p = atomicAdd(reinterpret_cast<unsigned*>(&acc[2]), 1u);
        list[p] = n;
    }
}

// One wave per ACTIVE row; wave = 4 groups x 16 lanes, one neighbor per group
// per slot, 13 slots, branch-free.
// FORCED MLP: the 13 row-gathers are issued as 13 ordered asm-volatile
// global_load_dwordx4 (compiler cannot sink them; round-2's C version was
// re-sunk, VGPR dropped to 52 and MLP never materialized). Decode of slot s
// sits behind a counted s_waitcnt vmcnt(12-s) + sched_barrier(0) (rule #18).
// All 208 gathered lines per wave are in flight instead of ~2.
__global__ __launch_bounds__(256) void row_loss_fp8(
    const float* __restrict__ emb,
    const uchar* __restrict__ tblb,
    const int* __restrict__ nbr,
    const int* __restrict__ nbrm,
    const int* __restrict__ neg,
    const int* __restrict__ list,
    float* __restrict__ acc) {
    __shared__ float s_num[4];
    const int wave = threadIdx.x >> 6;
    const int lane = threadIdx.x & 63;
    const int g = lane >> 4;
    const int t = lane & 15;

    const int cnt_active = reinterpret_cast<const int*>(acc)[2];
    const int i = blockIdx.x * 4 + wave;
    float num = 0.f;

    if (i < cnt_active) {  // wave-uniform
        const int n = list[i];

        // own row fp32 (exact), elems 16t..16t+15 (round-1 layout)
        const float4* erow = reinterpret_cast<const float4*>(emb + (size_t)n * kD);
        float4 own4[4];
#pragma unroll
        for (int j = 0; j < 4; ++j) {
            const float4 f = erow[4 * t + j];
            own4[j].x = f.x * kOwnScale;
            own4[j].y = f.y * kOwnScale;
            own4[j].z = f.z * kOwnScale;
            own4[j].w = f.w * kOwnScale;
        }

        const int* nrow = nbr + (size_t)n * kPos;
        const int* mrow = nbrm + (size_t)n * kPos;
        const int* grow = neg + (size_t)n * kNeg;

        uint off[kSlots];  // byte offsets into the table (idx*256 + t*16)
        float w[kPos / 4];
        float cnt = 0.f;
#pragma unroll
        for (int s = 0; s < kPos / 4; ++s) {
            off[s] = ((uint)nrow[s * 4 + g] << 8) + (uint)t * 16u;
            const float mf = (float)mrow[s * 4 + g];
            w[s] = mf;
            cnt += mf;
        }
#pragma unroll
        for (int s = 0; s < kNeg / 4; ++s)
            off[kPos / 4 + s] = ((uint)grow[s * 4 + g] << 8) + (uint)t * 16u;

        // Drain all prior vector loads (indices, own row) so (a) the compiler
        // has no pending-load accounting left and won't emit its own waitcnt
        // inside the pipelined region, and (b) our counted vmcnt values are
        // exact (only OUR 13 loads are outstanding past this point).
        asm volatile("s_waitcnt vmcnt(0)" ::: "memory");
        __builtin_amdgcn_sched_barrier(0);

        uintx4 uc[kSlots];
#define LOADS(s)                                                           \
    asm volatile("global_load_dwordx4 %0, %1, %2"                          \
                 : "=&v"(uc[s])                                            \
                 : "v"(off[s]), "s"(tblb)                                  \
                 : "memory")
        LOADS(0); LOADS(1); LOADS(2); LOADS(3); LOADS(4); LOADS(5);
        LOADS(6); LOADS(7); LOADS(8); LOADS(9); LOADS(10); LOADS(11);
        LOADS(12);
#undef LOADS

        float pos_sum = 0.f, neg_sum = 0.f;
#define PSLOT(s, nw)                                                       \
    do {                                                                   \
        asm volatile("s_waitcnt vmcnt(" #nw ")" ::: "memory");             \
        __builtin_amdgcn_sched_barrier(0);                                 \
        const float d = dot16(uc[s], own4);                                \
        const float sg = 1.f / (1.f + __expf(-d));                         \
        pos_sum += -__logf(sg + kEps) * w[s];                              \
    } while (0)
#define NSLOT(s, nw)                                                       \
    do {                                                                   \
        asm volatile("s_waitcnt vmcnt(" #nw ")" ::: "memory");             \
        __builtin_amdgcn_sched_barrier(0);                                 \
        const float d = dot16(uc[s], own4);                                \
        const float sg = 1.f / (1.f + __expf(-d));                         \
        neg_sum += -__logf(1.f - sg + kEps);                               \
    } while (0)
        PSLOT(0, 12); PSLOT(1, 11); PSLOT(2, 10); PSLOT(3, 9);
        PSLOT(4, 8);  PSLOT(5, 7);  PSLOT(6, 6);  PSLOT(7, 5);
        NSLOT(8, 4);  NSLOT(9, 3);  NSLOT(10, 2); NSLOT(11, 1);
        NSLOT(12, 0);
#undef PSLOT
#undef NSLOT

        // combine the 4 groups (each group's 16 lanes hold identical values)
        pos_sum += __shfl_xor(pos_sum, 16);
        pos_sum += __shfl_xor(pos_sum, 32);
        neg_sum += __shfl_xor(neg_sum, 16);
        neg_sum += __shfl_xor(neg_sum, 32);
        cnt += __shfl_xor(cnt, 16);
        cnt += __shfl_xor(cnt, 32);

        if (cnt > 0.f) num = pos_sum / cnt + neg_sum / (float)kNeg;
        // cnt==0 -> NaN row in reference -> replaced by 0 -> contributes 0
    }

    if (lane == 0) s_num[wave] = num;
    __syncthreads();
    if (threadIdx.x == 0) {
        const float v = s_num[0] + s_num[1] + s_num[2] + s_num[3];
        if (v != 0.f) atomicAdd(&acc[0], v);
    }
}

__global__ void finalize_kernel(const float* __restrict__ acc, float* __restrict__ out) {
    out[0] = acc[0] / (float)reinterpret_cast<const int*>(acc)[2];
}

// ---------- fp32 direct fallback (only if d_ws too small; UNCHANGED) ----------
__global__ __launch_bounds__(256) void row_loss_f32(
    const float* __restrict__ emb,
    const int* __restrict__ nbr,
    const int* __restrict__ nbrm,
    const int* __restrict__ neg,
    const int* __restrict__ rmask,
    float* __restrict__ acc) {
    __shared__ float s_num[4];
    __shared__ float s_den[4];
    const int wave = threadIdx.x >> 6;
    const int lane = threadIdx.x & 63;
    const int n = blockIdx.x * 4 + wave;
    const int g = lane >> 4;
    const int t = lane & 15;

    const float4* erow = reinterpret_cast<const float4*>(emb + (size_t)n * kD);
    float4 own4[4];
#pragma unroll
    for (int j = 0; j < 4; ++j) own4[j] = erow[j * 16 + t];

    const int* nrow = nbr + (size_t)n * kPos;
    const int* mrow = nbrm + (size_t)n * kPos;
    const int* grow = neg + (size_t)n * kNeg;

    float pos_sum = 0.f, neg_sum = 0.f, cnt = 0.f;
#pragma unroll
    for (int it = 0; it < kPos / 4; ++it) {
        const int idx = nrow[it * 4 + g];
        const float mf = (float)mrow[it * 4 + g];
        cnt += mf;
        const float4* brow = reinterpret_cast<const float4*>(emb + (size_t)idx * kD);
        float d = 0.f;
#pragma unroll
        for (int j = 0; j < 4; ++j) {
            const float4 b = brow[j * 16 + t];
            const float4 a = own4[j];
            d += a.x * b.x + a.y * b.y + a.z * b.z + a.w * b.w;
        }
        d += __shfl_xor(d, 8);
        d += __shfl_xor(d, 4);
        d += __shfl_xor(d, 2);
        d += __shfl_xor(d, 1);
        const float s = 1.f / (1.f + __expf(-d));
        pos_sum += -__logf(s + kEps) * mf;
    }
#pragma unroll
    for (int it = 0; it < kNeg / 4; ++it) {
        const int idx = grow[it * 4 + g];
        const float4* brow = reinterpret_cast<const float4*>(emb + (size_t)idx * kD);
        float d = 0.f;
#pragma unroll
        for (int j = 0; j < 4; ++j) {
            const float4 b = brow[j * 16 + t];
            const float4 a = own4[j];
            d += a.x * b.x + a.y * b.y + a.z * b.z + a.w * b.w;
        }
        d += __shfl_xor(d, 8);
        d += __shfl_xor(d, 4);
        d += __shfl_xor(d, 2);
        d += __shfl_xor(d, 1);
        const float s = 1.f / (1.f + __expf(-d));
        neg_sum += -__logf(1.f - s + kEps);
    }

    pos_sum += __shfl_xor(pos_sum, 16);
    pos_sum += __shfl_xor(pos_sum, 32);
    neg_sum += __shfl_xor(neg_sum, 16);
    neg_sum += __shfl_xor(neg_sum, 32);
    cnt += __shfl_xor(cnt, 16);
    cnt += __shfl_xor(cnt, 32);

    float num = 0.f;
    if (cnt > 0.f) num = pos_sum / cnt + neg_sum / (float)kNeg;
    const float rmf = (float)rmask[n];

    if (lane == 0) {
        s_num[wave] = num * rmf;
        s_den[wave] = rmf;
    }
    __syncthreads();
    if (threadIdx.x == 0) {
        atomicAdd(&acc[0], s_num[0] + s_num[1] + s_num[2] + s_num[3]);
        atomicAdd(&acc[1], s_den[0] + s_den[1] + s_den[2] + s_den[3]);
    }
}

__global__ void finalize_f32(const float* __restrict__ acc, float* __restrict__ out) {
    out[0] = acc[0] / acc[1];
}
}  // namespace

extern "C" void kernel_launch(void* const* d_in, const int* in_sizes, int n_in,
                              void* d_out, int out_size, void* d_ws, size_t ws_size,
                              hipStream_t stream) {
    const float* emb = (const float*)d_in[0];
    const int* nbr = (const int*)d_in[1];
    const int* nbrm = (const int*)d_in[2];
    const int* neg = (const int*)d_in[3];
    const int* rmask = (const int*)d_in[4];
    float* acc = (float*)d_ws;  // [0]=num, [1]=den, [2]=active count

    const size_t tbl_bytes = (size_t)kN * kD;  // 12.8 MB
    const size_t list_bytes = (size_t)kN * sizeof(int);
    if (ws_size >= 256 + tbl_bytes + list_bytes) {
        uint* tbl = (uint*)((char*)d_ws + 256);
        int* list = (int*)((char*)d_ws + 256 + tbl_bytes);
        hipMemsetAsync(acc, 0, 4 * sizeof(float), stream);
        compact_kernel<<<(kN + 255) / 256, 256, 0, stream>>>(rmask, list, acc);
        convert_fp8<<<kN * kD / 8 / 256, 256, 0, stream>>>(emb, tbl);
        row_loss_fp8<<<(kN + 3) / 4, 256, 0, stream>>>(emb, (const uchar*)tbl, nbr,
                                                       nbrm, neg, list, acc);
        finalize_kernel<<<1, 1, 0, stream>>>(acc, (float*)d_out);
    } else {
        hipMemsetAsync(acc, 0, 2 * sizeof(float), stream);
        row_loss_f32<<<kN / 4, 256, 0, stream>>>(emb, nbr, nbrm, neg, rmask, acc);
        finalize_f32<<<1, 1, 0, stream>>>(acc, (float*)d_out);
    }
}

// Round 6
// 201.662 us; speedup vs baseline: 1.0128x; 1.0054x over previous
//
#include <hip/hip_runtime.h>
#include <hip/hip_fp16.h>
#include <string.h>

namespace {
constexpr int kN = 50000;
constexpr int kD = 256;
constexpr int kPos = 32;
constexpr int kNeg = 20;
constexpr float kEps = 1e-15f;
constexpr int kSlots = kPos / 4 + kNeg / 4;  // 13 per 16-lane group

typedef float floatx2 __attribute__((ext_vector_type(2)));
typedef uint uintx4 __attribute__((ext_vector_type(4)));

#if __has_builtin(__builtin_amdgcn_cvt_pk_f32_fp8)
constexpr bool kHwCvtPk = true;
constexpr bool kHwCvt1 = false;
#elif __has_builtin(__builtin_amdgcn_cvt_f32_fp8)
constexpr bool kHwCvtPk = false;
constexpr bool kHwCvt1 = true;
#else
constexpr bool kHwCvtPk = false;
constexpr bool kHwCvt1 = false;
#endif
// software-decode fallback yields value*2^-8, so own must be pre-scaled by 256
constexpr float kOwnScale = (kHwCvtPk || kHwCvt1) ? 1.f : 256.f;

// ---------- software fp8 e4m3fn <-> f32 via the f16 bit-correspondence ----------
// ENCODE IS UNCHANGED: table bytes are bit-identical to the verified kernel.
__device__ __forceinline__ uint enc1(float x) {
    const __half hh = __float2half(x * 0.00390625f);  // x * 2^-8, HW RNE
    unsigned short t;
    memcpy(&t, &hh, 2);
    const uint s = ((uint)t >> 8) & 0x80u;
    uint mag = (uint)t & 0x7fffu;
    mag = mag + 0x3fu + ((mag >> 7) & 1u);  // RNE 10->3 bit mantissa
    uint u = mag >> 7;
    if (u > 0x7eu) u = 0x7eu;
    return s | u;
}

__device__ __forceinline__ float dec_h(uint h) {
    __half hh;
    const unsigned short t = (unsigned short)h;
    memcpy(&hh, &t, 2);
    return __half2float(hh);
}

// Decode 4 packed e4m3 bytes, accumulate dot with o.x..o.w into d.
__device__ __forceinline__ void dq4f(uint u, const float4& o, float& d) {
#if __has_builtin(__builtin_amdgcn_cvt_pk_f32_fp8)
    const floatx2 lo = __builtin_amdgcn_cvt_pk_f32_fp8((int)u, false);  // bytes 0,1
    const floatx2 hi = __builtin_amdgcn_cvt_pk_f32_fp8((int)u, true);   // bytes 2,3
    d = fmaf(lo.x, o.x, d);
    d = fmaf(lo.y, o.y, d);
    d = fmaf(hi.x, o.z, d);
    d = fmaf(hi.y, o.w, d);
#elif __has_builtin(__builtin_amdgcn_cvt_f32_fp8)
    d = fmaf(__builtin_amdgcn_cvt_f32_fp8((int)u, 0), o.x, d);
    d = fmaf(__builtin_amdgcn_cvt_f32_fp8((int)u, 1), o.y, d);
    d = fmaf(__builtin_amdgcn_cvt_f32_fp8((int)u, 2), o.z, d);
    d = fmaf(__builtin_amdgcn_cvt_f32_fp8((int)u, 3), o.w, d);
#else
    const float v0 = dec_h(((u << 8) & 0x8000u) | ((u << 7) & 0x3f80u));
    const float v1 = dec_h((u & 0x8000u) | ((u >> 1) & 0x3f80u));
    const float v2 = dec_h(((u >> 8) & 0x8000u) | ((u >> 9) & 0x3f80u));
    const float v3 = dec_h(((u >> 16) & 0x8000u) | ((u >> 17) & 0x3f80u));
    d = fmaf(v0, o.x, d);
    d = fmaf(v1, o.y, d);
    d = fmaf(v2, o.z, d);
    d = fmaf(v3, o.w, d);
#endif
}

// dot over this lane's 16 elems + 16-lane-group reduce (same op order as the
// verified round-1 kernel -> bit-identical result).
__device__ __forceinline__ float dot16(const uintx4 u, const float4* o) {
    float d = 0.f;
    dq4f(u[0], o[0], d);
    dq4f(u[1], o[1], d);
    dq4f(u[2], o[2], d);
    dq4f(u[3], o[3], d);
    d += __shfl_xor(d, 8);
    d += __shfl_xor(d, 4);
    d += __shfl_xor(d, 2);
    d += __shfl_xor(d, 1);
    return d;
}

// ---------- fp32 -> fp8 table; 8 elems/thread (UNCHANGED) ----------
__global__ __launch_bounds__(256) void convert_fp8(const float* __restrict__ emb,
                                                   uint* __restrict__ tbl) {
    const size_t i = ((size_t)blockIdx.x * 256 + threadIdx.x) * 8;
    const float4* src = reinterpret_cast<const float4*>(emb + i);
    const float4 a = src[0];
    const float4 b = src[1];
    uint2 o;
    o.x = enc1(a.x) | (enc1(a.y) << 8) | (enc1(a.z) << 16) | (enc1(a.w) << 24);
    o.y = enc1(b.x) | (enc1(b.y) << 8) | (enc1(b.z) << 16) | (enc1(b.w) << 24);
    reinterpret_cast<uint2*>(tbl)[i / 8] = o;
}

// ---------- active-row compaction (order irrelevant) ----------
__global__ __launch_bounds__(256) void compact_kernel(const int* __restrict__ rmask,
                                                      int* __restrict__ list,
                                                      float* __restrict__ acc) {
    const int n = blockIdx.x * 256 + threadIdx.x;
    if (n < kN && rmask[n]) {
        const int p = atomicAdd(reinterpret_cast<unsigned*>(&acc[2]), 1u);
        list[p] = n;
    }
}

// One wave per ACTIVE row; wave = 4 groups x 16 lanes, one neighbor per group
// per slot, 13 slots, branch-free.
// 6-DEEP ROTATING PIPELINE (forced via asm): round-5's 13-deep version spilled
// (VGPR stayed 48 < 52 needed), and spilling a loaded value forces a wait ->
// serialization. Depth 6 needs only 24 payload VGPRs; __launch_bounds__(256,4)
// raises the allocator cap to 128 VGPRs so nothing spills. All issues/waits
// are asm volatile => program order guaranteed => counted vmcnt exact.
// Materialization check: VGPR_Count must rise to ~64-96.
__global__ __launch_bounds__(256, 4) void row_loss_fp8(
    const float* __restrict__ emb,
    const uchar* __restrict__ tblb,
    const int* __restrict__ nbr,
    const int* __restrict__ nbrm,
    const int* __restrict__ neg,
    const int* __restrict__ list,
    float* __restrict__ acc) {
    __shared__ float s_num[4];
    const int wave = threadIdx.x >> 6;
    const int lane = threadIdx.x & 63;
    const int g = lane >> 4;
    const int t = lane & 15;

    const int cnt_active = reinterpret_cast<const int*>(acc)[2];
    const int i = blockIdx.x * 4 + wave;
    float num = 0.f;

    if (i < cnt_active) {  // wave-uniform
        const int n = list[i];

        // own row fp32 (exact), elems 16t..16t+15 (round-1 layout)
        const float4* erow = reinterpret_cast<const float4*>(emb + (size_t)n * kD);
        float4 own4[4];
#pragma unroll
        for (int j = 0; j < 4; ++j) {
            const float4 f = erow[4 * t + j];
            own4[j].x = f.x * kOwnScale;
            own4[j].y = f.y * kOwnScale;
            own4[j].z = f.z * kOwnScale;
            own4[j].w = f.w * kOwnScale;
        }

        const int* nrow = nbr + (size_t)n * kPos;
        const int* mrow = nbrm + (size_t)n * kPos;
        const int* grow = neg + (size_t)n * kNeg;

        uint off[kSlots];  // byte offsets into the table (idx*256 + t*16)
        float w[kPos / 4];
        float cnt = 0.f;
#pragma unroll
        for (int s = 0; s < kPos / 4; ++s) {
            off[s] = ((uint)nrow[s * 4 + g] << 8) + (uint)t * 16u;
            const float mf = (float)mrow[s * 4 + g];
            w[s] = mf;
            cnt += mf;
        }
#pragma unroll
        for (int s = 0; s < kNeg / 4; ++s)
            off[kPos / 4 + s] = ((uint)grow[s * 4 + g] << 8) + (uint)t * 16u;

        // Drain all prior vector loads so only OUR pipeline loads are
        // outstanding and the counted vmcnt values below are exact.
        asm volatile("s_waitcnt vmcnt(0)" ::: "memory");
        __builtin_amdgcn_sched_barrier(0);

        uintx4 uc0, uc1, uc2, uc3, uc4, uc5;
        float pos_sum = 0.f, neg_sum = 0.f;

#define ISSUE(sidx, B)                                                      \
    asm volatile("global_load_dwordx4 %0, %1, %2"                           \
                 : "=&v"(uc##B)                                             \
                 : "v"(off[sidx]), "s"(tblb)                                \
                 : "memory")
#define WAITN(nw)                                                           \
    do {                                                                    \
        asm volatile("s_waitcnt vmcnt(" #nw ")" ::: "memory");              \
        __builtin_amdgcn_sched_barrier(0);                                  \
    } while (0)
#define PBODY(s, B)                                                         \
    do {                                                                    \
        const float d = dot16(uc##B, own4);                                 \
        const float sg = 1.f / (1.f + __expf(-d));                          \
        pos_sum += -__logf(sg + kEps) * w[s];                               \
    } while (0)
#define NBODY(s, B)                                                         \
    do {                                                                    \
        const float d = dot16(uc##B, own4);                                 \
        const float sg = 1.f / (1.f + __expf(-d));                          \
        neg_sum += -__logf(1.f - sg + kEps);                                \
    } while (0)

        // prologue: 6 loads in flight
        ISSUE(0, 0); ISSUE(1, 1); ISSUE(2, 2); ISSUE(3, 3); ISSUE(4, 4);
        ISSUE(5, 5);
        // steady state: wait oldest, decode, reissue freed buffer
        WAITN(5); PBODY(0, 0); ISSUE(6, 0);
        WAITN(5); PBODY(1, 1); ISSUE(7, 1);
        WAITN(5); PBODY(2, 2); ISSUE(8, 2);
        WAITN(5); PBODY(3, 3); ISSUE(9, 3);
        WAITN(5); PBODY(4, 4); ISSUE(10, 4);
        WAITN(5); PBODY(5, 5); ISSUE(11, 5);
        WAITN(5); PBODY(6, 0); ISSUE(12, 0);
        WAITN(5); PBODY(7, 1);
        // drain tail
        WAITN(4); NBODY(8, 2);
        WAITN(3); NBODY(9, 3);
        WAITN(2); NBODY(10, 4);
        WAITN(1); NBODY(11, 5);
        WAITN(0); NBODY(12, 0);

#undef ISSUE
#undef WAITN
#undef PBODY
#undef NBODY

        // combine the 4 groups (each group's 16 lanes hold identical values)
        pos_sum += __shfl_xor(pos_sum, 16);
        pos_sum += __shfl_xor(pos_sum, 32);
        neg_sum += __shfl_xor(neg_sum, 16);
        neg_sum += __shfl_xor(neg_sum, 32);
        cnt += __shfl_xor(cnt, 16);
        cnt += __shfl_xor(cnt, 32);

        if (cnt > 0.f) num = pos_sum / cnt + neg_sum / (float)kNeg;
        // cnt==0 -> NaN row in reference -> replaced by 0 -> contributes 0
    }

    if (lane == 0) s_num[wave] = num;
    __syncthreads();
    if (threadIdx.x == 0) {
        const float v = s_num[0] + s_num[1] + s_num[2] + s_num[3];
        if (v != 0.f) atomicAdd(&acc[0], v);
    }
}

__global__ void finalize_kernel(const float* __restrict__ acc, float* __restrict__ out) {
    out[0] = acc[0] / (float)reinterpret_cast<const int*>(acc)[2];
}

// ---------- fp32 direct fallback (only if d_ws too small; UNCHANGED) ----------
__global__ __launch_bounds__(256) void row_loss_f32(
    const float* __restrict__ emb,
    const int* __restrict__ nbr,
    const int* __restrict__ nbrm,
    const int* __restrict__ neg,
    const int* __restrict__ rmask,
    float* __restrict__ acc) {
    __shared__ float s_num[4];
    __shared__ float s_den[4];
    const int wave = threadIdx.x >> 6;
    const int lane = threadIdx.x & 63;
    const int n = blockIdx.x * 4 + wave;
    const int g = lane >> 4;
    const int t = lane & 15;

    const float4* erow = reinterpret_cast<const float4*>(emb + (size_t)n * kD);
    float4 own4[4];
#pragma unroll
    for (int j = 0; j < 4; ++j) own4[j] = erow[j * 16 + t];

    const int* nrow = nbr + (size_t)n * kPos;
    const int* mrow = nbrm + (size_t)n * kPos;
    const int* grow = neg + (size_t)n * kNeg;

    float pos_sum = 0.f, neg_sum = 0.f, cnt = 0.f;
#pragma unroll
    for (int it = 0; it < kPos / 4; ++it) {
        const int idx = nrow[it * 4 + g];
        const float mf = (float)mrow[it * 4 + g];
        cnt += mf;
        const float4* brow = reinterpret_cast<const float4*>(emb + (size_t)idx * kD);
        float d = 0.f;
#pragma unroll
        for (int j = 0; j < 4; ++j) {
            const float4 b = brow[j * 16 + t];
            const float4 a = own4[j];
            d += a.x * b.x + a.y * b.y + a.z * b.z + a.w * b.w;
        }
        d += __shfl_xor(d, 8);
        d += __shfl_xor(d, 4);
        d += __shfl_xor(d, 2);
        d += __shfl_xor(d, 1);
        const float s = 1.f / (1.f + __expf(-d));
        pos_sum += -__logf(s + kEps) * mf;
    }
#pragma unroll
    for (int it = 0; it < kNeg / 4; ++it) {
        const int idx = grow[it * 4 + g];
        const float4* brow = reinterpret_cast<const float4*>(emb + (size_t)idx * kD);
        float d = 0.f;
#pragma unroll
        for (int j = 0; j < 4; ++j) {
            const float4 b = brow[j * 16 + t];
            const float4 a = own4[j];
            d += a.x * b.x + a.y * b.y + a.z * b.z + a.w * b.w;
        }
        d += __shfl_xor(d, 8);
        d += __shfl_xor(d, 4);
        d += __shfl_xor(d, 2);
        d += __shfl_xor(d, 1);
        const float s = 1.f / (1.f + __expf(-d));
        neg_sum += -__logf(1.f - s + kEps);
    }

    pos_sum += __shfl_xor(pos_sum, 16);
    pos_sum += __shfl_xor(pos_sum, 32);
    neg_sum += __shfl_xor(neg_sum, 16);
    neg_sum += __shfl_xor(neg_sum, 32);
    cnt += __shfl_xor(cnt, 16);
    cnt += __shfl_xor(cnt, 32);

    float num = 0.f;
    if (cnt > 0.f) num = pos_sum / cnt + neg_sum / (float)kNeg;
    const float rmf = (float)rmask[n];

    if (lane == 0) {
        s_num[wave] = num * rmf;
        s_den[wave] = rmf;
    }
    __syncthreads();
    if (threadIdx.x == 0) {
        atomicAdd(&acc[0], s_num[0] + s_num[1] + s_num[2] + s_num[3]);
        atomicAdd(&acc[1], s_den[0] + s_den[1] + s_den[2] + s_den[3]);
    }
}

__global__ void finalize_f32(const float* __restrict__ acc, float* __restrict__ out) {
    out[0] = acc[0] / acc[1];
}
}  // namespace

extern "C" void kernel_launch(void* const* d_in, const int* in_sizes, int n_in,
                              void* d_out, int out_size, void* d_ws, size_t ws_size,
                              hipStream_t stream) {
    const float* emb = (const float*)d_in[0];
    const int* nbr = (const int*)d_in[1];
    const int* nbrm = (const int*)d_in[2];
    const int* neg = (const int*)d_in[3];
    const int* rmask = (const int*)d_in[4];
    float* acc = (float*)d_ws;  // [0]=num, [1]=den, [2]=active count

    const size_t tbl_bytes = (size_t)kN * kD;  // 12.8 MB
    const size_t list_bytes = (size_t)kN * sizeof(int);
    if (ws_size >= 256 + tbl_bytes + list_bytes) {
        uint* tbl = (uint*)((char*)d_ws + 256);
        int* list = (int*)((char*)d_ws + 256 + tbl_bytes);
        hipMemsetAsync(acc, 0, 4 * sizeof(float), stream);
        compact_kernel<<<(kN + 255) / 256, 256, 0, stream>>>(rmask, list, acc);
        convert_fp8<<<kN * kD / 8 / 256, 256, 0, stream>>>(emb, tbl);
        row_loss_fp8<<<(kN + 3) / 4, 256, 0, stream>>>(emb, (const uchar*)tbl, nbr,
                                                       nbrm, neg, list, acc);
        finalize_kernel<<<1, 1, 0, stream>>>(acc, (float*)d_out);
    } else {
        hipMemsetAsync(acc, 0, 2 * sizeof(float), stream);
        row_loss_f32<<<kN / 4, 256, 0, stream>>>(emb, nbr, nbrm, neg, rmask, acc);
        finalize_f32<<<1, 1, 0, stream>>>(acc, (float*)d_out);
    }
}

// Round 8
// 196.883 us; speedup vs baseline: 1.0374x; 1.0243x over previous
//
#include <hip/hip_runtime.h>
#include <hip/hip_fp16.h>
#include <string.h>

namespace {
constexpr int kN = 50000;
constexpr int kD = 256;
constexpr int kPos = 32;
constexpr int kNeg = 20;
constexpr float kEps = 1e-15f;
constexpr int kSlots = kPos / 4 + kNeg / 4;  // 13 per 16-lane group
constexpr int kCompactBlocks = (kN + 255) / 256;   // 196
constexpr int kConvertBlocks = kN * kD / 8 / 256;  // 6250

typedef float floatx2 __attribute__((ext_vector_type(2)));

#if __has_builtin(__builtin_amdgcn_cvt_pk_f32_fp8)
constexpr bool kHwCvtPk = true;
constexpr bool kHwCvt1 = false;
#elif __has_builtin(__builtin_amdgcn_cvt_f32_fp8)
constexpr bool kHwCvtPk = false;
constexpr bool kHwCvt1 = true;
#else
constexpr bool kHwCvtPk = false;
constexpr bool kHwCvt1 = false;
#endif
// software-decode fallback yields value*2^-8, so own must be pre-scaled by 256
constexpr float kOwnScale = (kHwCvtPk || kHwCvt1) ? 1.f : 256.f;

// ---------- software fp8 e4m3fn <-> f32 via the f16 bit-correspondence ----------
// ENCODE IS UNCHANGED: table bytes are bit-identical to the verified kernel.
__device__ __forceinline__ uint enc1(float x) {
    const __half hh = __float2half(x * 0.00390625f);  // x * 2^-8, HW RNE
    unsigned short t;
    memcpy(&t, &hh, 2);
    const uint s = ((uint)t >> 8) & 0x80u;
    uint mag = (uint)t & 0x7fffu;
    mag = mag + 0x3fu + ((mag >> 7) & 1u);  // RNE 10->3 bit mantissa
    uint u = mag >> 7;
    if (u > 0x7eu) u = 0x7eu;
    return s | u;
}

__device__ __forceinline__ float dec_h(uint h) {
    __half hh;
    const unsigned short t = (unsigned short)h;
    memcpy(&hh, &t, 2);
    return __half2float(hh);
}

// Decode 4 packed e4m3 bytes and accumulate dot with o[0..3].
__device__ __forceinline__ void dq4(uint u, const float* o, float& d) {
#if __has_builtin(__builtin_amdgcn_cvt_pk_f32_fp8)
    const floatx2 lo = __builtin_amdgcn_cvt_pk_f32_fp8((int)u, false);  // bytes 0,1
    const floatx2 hi = __builtin_amdgcn_cvt_pk_f32_fp8((int)u, true);   // bytes 2,3
    d = fmaf(lo.x, o[0], d);
    d = fmaf(lo.y, o[1], d);
    d = fmaf(hi.x, o[2], d);
    d = fmaf(hi.y, o[3], d);
#elif __has_builtin(__builtin_amdgcn_cvt_f32_fp8)
    d = fmaf(__builtin_amdgcn_cvt_f32_fp8((int)u, 0), o[0], d);
    d = fmaf(__builtin_amdgcn_cvt_f32_fp8((int)u, 1), o[1], d);
    d = fmaf(__builtin_amdgcn_cvt_f32_fp8((int)u, 2), o[2], d);
    d = fmaf(__builtin_amdgcn_cvt_f32_fp8((int)u, 3), o[3], d);
#else
    const float v0 = dec_h(((u << 8) & 0x8000u) | ((u << 7) & 0x3f80u));
    const float v1 = dec_h((u & 0x8000u) | ((u >> 1) & 0x3f80u));
    const float v2 = dec_h(((u >> 8) & 0x8000u) | ((u >> 9) & 0x3f80u));
    const float v3 = dec_h(((u >> 16) & 0x8000u) | ((u >> 17) & 0x3f80u));
    d = fmaf(v0, o[0], d);
    d = fmaf(v1, o[1], d);
    d = fmaf(v2, o[2], d);
    d = fmaf(v3, o[3], d);
#endif
}

// ---------- fused prep: compaction + fp8 convert + out zeroing ----------
// Blocks 0..195: active-row compaction (order irrelevant). Block 0 also zeroes
// out[0] (row_loss only runs after prep completes, stream-ordered).
// Blocks 196..6445: fp32 -> fp8 table, 8 elems/thread (encode unchanged).
__global__ __launch_bounds__(256) void prep_kernel(const float* __restrict__ emb,
                                                   uint* __restrict__ tbl,
                                                   const int* __restrict__ rmask,
                                                   int* __restrict__ list,
                                                   float* __restrict__ acc,
                                                   float* __restrict__ out) {
    const int bid = blockIdx.x;
    if (bid < kCompactBlocks) {
        if (bid == 0 && threadIdx.x == 0) out[0] = 0.f;
        const int n = bid * 256 + threadIdx.x;
        if (n < kN && rmask[n]) {
            const int p = atomicAdd(reinterpret_cast<unsigned*>(&acc[2]), 1u);
            list[p] = n;
        }
    } else {
        const size_t i = ((size_t)(bid - kCompactBlocks) * 256 + threadIdx.x) * 8;
        const float4* src = reinterpret_cast<const float4*>(emb + i);
        const float4 a = src[0];
        const float4 b = src[1];
        uint2 o;
        o.x = enc1(a.x) | (enc1(a.y) << 8) | (enc1(a.z) << 16) | (enc1(a.w) << 24);
        o.y = enc1(b.x) | (enc1(b.y) << 8) | (enc1(b.z) << 16) | (enc1(b.w) << 24);
        reinterpret_cast<uint2*>(tbl)[i / 8] = o;
    }
}

// One wave per ACTIVE row (round-1 verified body: HW cvt_pk decode, 32-bit
// offsets, 1-deep prefetch — best measured at 93.0 us). The final divide by
// cnt_active is folded into each block's single atomicAdd to out[0]
// (out zeroed by prep), eliminating the finalize dispatch.
__global__ __launch_bounds__(256) void row_loss_fp8(
    const float* __restrict__ emb,
    const uchar* __restrict__ tblb,
    const int* __restrict__ nbr,
    const int* __restrict__ nbrm,
    const int* __restrict__ neg,
    const int* __restrict__ list,
    const float* __restrict__ acc,
    float* __restrict__ out) {
    __shared__ float s_num[4];
    const int wave = threadIdx.x >> 6;
    const int lane = threadIdx.x & 63;
    const int g = lane >> 4;
    const int t = lane & 15;
    const uint lane_off = (uint)t * 16u;

    const int cnt_active = reinterpret_cast<const int*>(acc)[2];
    const int i = blockIdx.x * 4 + wave;
    float num = 0.f;

    if (i < cnt_active) {  // wave-uniform
        const int n = list[i];

        // own row fp32 (exact), elems 16t..16t+15
        const float4* erow = reinterpret_cast<const float4*>(emb + (size_t)n * kD);
        float own[16];
#pragma unroll
        for (int j = 0; j < 4; ++j) {
            const float4 f = erow[4 * t + j];
            own[4 * j + 0] = f.x * kOwnScale;
            own[4 * j + 1] = f.y * kOwnScale;
            own[4 * j + 2] = f.z * kOwnScale;
            own[4 * j + 3] = f.w * kOwnScale;
        }

        const int* nrow = nbr + (size_t)n * kPos;
        const int* mrow = nbrm + (size_t)n * kPos;
        const int* grow = neg + (size_t)n * kNeg;

        // preload all offsets + weights: keeps the slot loop branch-free and
        // lets the compiler software-pipeline the gathers.
        uint off[kSlots];  // 32-bit byte offsets into the 12.8 MB table
        float w[kPos / 4];
        float cnt = 0.f;
#pragma unroll
        for (int s = 0; s < kPos / 4; ++s) {
            off[s] = ((uint)nrow[s * 4 + g] << 8) + lane_off;
            const float mf = (float)mrow[s * 4 + g];
            w[s] = mf;
            cnt += mf;
        }
#pragma unroll
        for (int s = 0; s < kNeg / 4; ++s)
            off[kPos / 4 + s] = ((uint)grow[s * 4 + g] << 8) + lane_off;

        float pos_sum = 0.f, neg_sum = 0.f;
        // 1-deep explicit prefetch: next slot's 16B gather is in flight while
        // the current slot decodes/reduces.
        uint4 u = *reinterpret_cast<const uint4*>(tblb + off[0]);
#pragma unroll
        for (int s = 0; s < kSlots; ++s) {
            const uint4 uc = u;
            if (s + 1 < kSlots)
                u = *reinterpret_cast<const uint4*>(tblb + off[s + 1]);
            float d = 0.f;
            dq4(uc.x, own + 0, d);
            dq4(uc.y, own + 4, d);
            dq4(uc.z, own + 8, d);
            dq4(uc.w, own + 12, d);
            d += __shfl_xor(d, 8);
            d += __shfl_xor(d, 4);
            d += __shfl_xor(d, 2);
            d += __shfl_xor(d, 1);
            const float sg = 1.f / (1.f + __expf(-d));
            if (s < kPos / 4) {  // compile-time branch (fully unrolled)
                pos_sum += -__logf(sg + kEps) * w[s];
            } else {
                neg_sum += -__logf(1.f - sg + kEps);
            }
        }

        // combine the 4 groups (each group's 16 lanes hold identical values)
        pos_sum += __shfl_xor(pos_sum, 16);
        pos_sum += __shfl_xor(pos_sum, 32);
        neg_sum += __shfl_xor(neg_sum, 16);
        neg_sum += __shfl_xor(neg_sum, 32);
        cnt += __shfl_xor(cnt, 16);
        cnt += __shfl_xor(cnt, 32);

        if (cnt > 0.f) num = pos_sum / cnt + neg_sum / (float)kNeg;
        // cnt==0 -> NaN row in reference -> replaced by 0 -> contributes 0
    }

    if (lane == 0) s_num[wave] = num;
    __syncthreads();
    if (threadIdx.x == 0) {
        const float v = s_num[0] + s_num[1] + s_num[2] + s_num[3];
        // fold the final /cnt_active into the accumulation (out zeroed by prep)
        if (v != 0.f) atomicAdd(out, v / (float)cnt_active);
    }
}

// ---------- fp32 direct fallback (only if d_ws too small; UNCHANGED) ----------
__global__ __launch_bounds__(256) void row_loss_f32(
    const float* __restrict__ emb,
    const int* __restrict__ nbr,
    const int* __restrict__ nbrm,
    const int* __restrict__ neg,
    const int* __restrict__ rmask,
    float* __restrict__ acc) {
    __shared__ float s_num[4];
    __shared__ float s_den[4];
    const int wave = threadIdx.x >> 6;
    const int lane = threadIdx.x & 63;
    const int n = blockIdx.x * 4 + wave;
    const int g = lane >> 4;
    const int t = lane & 15;

    const float4* erow = reinterpret_cast<const float4*>(emb + (size_t)n * kD);
    float4 own4[4];
#pragma unroll
    for (int j = 0; j < 4; ++j) own4[j] = erow[j * 16 + t];

    const int* nrow = nbr + (size_t)n * kPos;
    const int* mrow = nbrm + (size_t)n * kPos;
    const int* grow = neg + (size_t)n * kNeg;

    float pos_sum = 0.f, neg_sum = 0.f, cnt = 0.f;
#pragma unroll
    for (int it = 0; it < kPos / 4; ++it) {
        const int idx = nrow[it * 4 + g];
        const float mf = (float)mrow[it * 4 + g];
        cnt += mf;
        const float4* brow = reinterpret_cast<const float4*>(emb + (size_t)idx * kD);
        float d = 0.f;
#pragma unroll
        for (int j = 0; j < 4; ++j) {
            const float4 b = brow[j * 16 + t];
            const float4 a = own4[j];
            d += a.x * b.x + a.y * b.y + a.z * b.z + a.w * b.w;
        }
        d += __shfl_xor(d, 8);
        d += __shfl_xor(d, 4);
        d += __shfl_xor(d, 2);
        d += __shfl_xor(d, 1);
        const float s = 1.f / (1.f + __expf(-d));
        pos_sum += -__logf(s + kEps) * mf;
    }
#pragma unroll
    for (int it = 0; it < kNeg / 4; ++it) {
        const int idx = grow[it * 4 + g];
        const float4* brow = reinterpret_cast<const float4*>(emb + (size_t)idx * kD);
        float d = 0.f;
#pragma unroll
        for (int j = 0; j < 4; ++j) {
            const float4 b = brow[j * 16 + t];
            const float4 a = own4[j];
            d += a.x * b.x + a.y * b.y + a.z * b.z + a.w * b.w;
        }
        d += __shfl_xor(d, 8);
        d += __shfl_xor(d, 4);
        d += __shfl_xor(d, 2);
        d += __shfl_xor(d, 1);
        const float s = 1.f / (1.f + __expf(-d));
        neg_sum += -__logf(1.f - s + kEps);
    }

    pos_sum += __shfl_xor(pos_sum, 16);
    pos_sum += __shfl_xor(pos_sum, 32);
    neg_sum += __shfl_xor(neg_sum, 16);
    neg_sum += __shfl_xor(neg_sum, 32);
    cnt += __shfl_xor(cnt, 16);
    cnt += __shfl_xor(cnt, 32);

    float num = 0.f;
    if (cnt > 0.f) num = pos_sum / cnt + neg_sum / (float)kNeg;
    const float rmf = (float)rmask[n];

    if (lane == 0) {
        s_num[wave] = num * rmf;
        s_den[wave] = rmf;
    }
    __syncthreads();
    if (threadIdx.x == 0) {
        atomicAdd(&acc[0], s_num[0] + s_num[1] + s_num[2] + s_num[3]);
        atomicAdd(&acc[1], s_den[0] + s_den[1] + s_den[2] + s_den[3]);
    }
}

__global__ void finalize_f32(const float* __restrict__ acc, float* __restrict__ out) {
    out[0] = acc[0] / acc[1];
}
}  // namespace

extern "C" void kernel_launch(void* const* d_in, const int* in_sizes, int n_in,
                              void* d_out, int out_size, void* d_ws, size_t ws_size,
                              hipStream_t stream) {
    const float* emb = (const float*)d_in[0];
    const int* nbr = (const int*)d_in[1];
    const int* nbrm = (const int*)d_in[2];
    const int* neg = (const int*)d_in[3];
    const int* rmask = (const int*)d_in[4];
    float* acc = (float*)d_ws;  // [0]=num, [1]=den, [2]=active count

    const size_t tbl_bytes = (size_t)kN * kD;  // 12.8 MB
    const size_t list_bytes = (size_t)kN * sizeof(int);
    if (ws_size >= 256 + tbl_bytes + list_bytes) {
        uint* tbl = (uint*)((char*)d_ws + 256);
        int* list = (int*)((char*)d_ws + 256 + tbl_bytes);
        hipMemsetAsync(acc, 0, 4 * sizeof(float), stream);
        prep_kernel<<<kCompactBlocks + kConvertBlocks, 256, 0, stream>>>(
            emb, tbl, rmask, list, acc, (float*)d_out);
        row_loss_fp8<<<(kN + 3) / 4, 256, 0, stream>>>(emb, (const uchar*)tbl, nbr,
                                                       nbrm, neg, list, acc,
                                                       (float*)d_out);
    } else {
        hipMemsetAsync(acc, 0, 2 * sizeof(float), stream);
        row_loss_f32<<<kN / 4, 256, 0, stream>>>(emb, nbr, nbrm, neg, rmask, acc);
        finalize_f32<<<1, 1, 0, stream>>>(acc, (float*)d_out);
    }
}

// Round 9
// 194.879 us; speedup vs baseline: 1.0481x; 1.0103x over previous
//
#include <hip/hip_runtime.h>
#include <hip/hip_fp16.h>
#include <string.h>

namespace {
constexpr int kN = 50000;
constexpr int kD = 256;
constexpr int kPos = 32;
constexpr int kNeg = 20;
constexpr float kEps = 1e-15f;
constexpr int kSlots = kPos / 4 + kNeg / 4;  // 13 per 16-lane group
constexpr int kCompactBlocks = (kN + 255) / 256;   // 196
constexpr int kConvertBlocks = kN * kD / 8 / 256;  // 6250

typedef float floatx2 __attribute__((ext_vector_type(2)));

#if __has_builtin(__builtin_amdgcn_cvt_pk_f32_fp8)
constexpr bool kHwCvtPk = true;
constexpr bool kHwCvt1 = false;
#elif __has_builtin(__builtin_amdgcn_cvt_f32_fp8)
constexpr bool kHwCvtPk = false;
constexpr bool kHwCvt1 = true;
#else
constexpr bool kHwCvtPk = false;
constexpr bool kHwCvt1 = false;
#endif
// software-decode fallback yields value*2^-8, so own must be pre-scaled by 256
constexpr float kOwnScale = (kHwCvtPk || kHwCvt1) ? 1.f : 256.f;

// ---------- fp8 e4m3fn encode ----------
// Software path (f16 bit-correspondence): ~12 VALU ops/elem -> the prep kernel
// was VALU-bound at ~90+ us (inferred round 8: e2e-minus-row_loss accounting;
// 12.8M elems x 12 ops / 1024 SIMDs x 2cyc ~ 125 us issue floor).
// Hardware path: v_cvt_pk_fp8_f32 converts 2 f32 -> 2 e4m3fn bytes in ONE
// instruction (single-rounded RNE + saturation). Both paths store e4m3(x) at
// value scale 1, so the decode side is unchanged; they differ only on rare
// double-rounding ties (~2^-12 of elements, 1 fp8-ULP).
__device__ __forceinline__ uint enc1(float x) {
    const __half hh = __float2half(x * 0.00390625f);  // x * 2^-8, HW RNE
    unsigned short t;
    memcpy(&t, &hh, 2);
    const uint s = ((uint)t >> 8) & 0x80u;
    uint mag = (uint)t & 0x7fffu;
    mag = mag + 0x3fu + ((mag >> 7) & 1u);  // RNE 10->3 bit mantissa
    uint u = mag >> 7;
    if (u > 0x7eu) u = 0x7eu;
    return s | u;
}

__device__ __forceinline__ uint enc4(const float4 a) {
#if __has_builtin(__builtin_amdgcn_cvt_pk_fp8_f32)
    int u = __builtin_amdgcn_cvt_pk_fp8_f32(a.x, a.y, 0, false);    // bytes 0,1
    u = __builtin_amdgcn_cvt_pk_fp8_f32(a.z, a.w, u, true);         // bytes 2,3
    return (uint)u;
#else
    return enc1(a.x) | (enc1(a.y) << 8) | (enc1(a.z) << 16) | (enc1(a.w) << 24);
#endif
}

__device__ __forceinline__ float dec_h(uint h) {
    __half hh;
    const unsigned short t = (unsigned short)h;
    memcpy(&hh, &t, 2);
    return __half2float(hh);
}

// Decode 4 packed e4m3 bytes and accumulate dot with o[0..3].
__device__ __forceinline__ void dq4(uint u, const float* o, float& d) {
#if __has_builtin(__builtin_amdgcn_cvt_pk_f32_fp8)
    const floatx2 lo = __builtin_amdgcn_cvt_pk_f32_fp8((int)u, false);  // bytes 0,1
    const floatx2 hi = __builtin_amdgcn_cvt_pk_f32_fp8((int)u, true);   // bytes 2,3
    d = fmaf(lo.x, o[0], d);
    d = fmaf(lo.y, o[1], d);
    d = fmaf(hi.x, o[2], d);
    d = fmaf(hi.y, o[3], d);
#elif __has_builtin(__builtin_amdgcn_cvt_f32_fp8)
    d = fmaf(__builtin_amdgcn_cvt_f32_fp8((int)u, 0), o[0], d);
    d = fmaf(__builtin_amdgcn_cvt_f32_fp8((int)u, 1), o[1], d);
    d = fmaf(__builtin_amdgcn_cvt_f32_fp8((int)u, 2), o[2], d);
    d = fmaf(__builtin_amdgcn_cvt_f32_fp8((int)u, 3), o[3], d);
#else
    const float v0 = dec_h(((u << 8) & 0x8000u) | ((u << 7) & 0x3f80u));
    const float v1 = dec_h((u & 0x8000u) | ((u >> 1) & 0x3f80u));
    const float v2 = dec_h(((u >> 8) & 0x8000u) | ((u >> 9) & 0x3f80u));
    const float v3 = dec_h(((u >> 16) & 0x8000u) | ((u >> 17) & 0x3f80u));
    d = fmaf(v0, o[0], d);
    d = fmaf(v1, o[1], d);
    d = fmaf(v2, o[2], d);
    d = fmaf(v3, o[3], d);
#endif
}

// ---------- fused prep: compaction + fp8 convert + out zeroing ----------
// Blocks 0..195: active-row compaction (order irrelevant). Block 0 also zeroes
// out[0] (row_loss only runs after prep completes, stream-ordered).
// Blocks 196..6445: fp32 -> fp8 table, 8 elems/thread, HW cvt_pk encode.
__global__ __launch_bounds__(256) void prep_kernel(const float* __restrict__ emb,
                                                   uint* __restrict__ tbl,
                                                   const int* __restrict__ rmask,
                                                   int* __restrict__ list,
                                                   float* __restrict__ acc,
                                                   float* __restrict__ out) {
    const int bid = blockIdx.x;
    if (bid < kCompactBlocks) {
        if (bid == 0 && threadIdx.x == 0) out[0] = 0.f;
        const int n = bid * 256 + threadIdx.x;
        if (n < kN && rmask[n]) {
            const int p = atomicAdd(reinterpret_cast<unsigned*>(&acc[2]), 1u);
            list[p] = n;
        }
    } else {
        const size_t i = ((size_t)(bid - kCompactBlocks) * 256 + threadIdx.x) * 8;
        const float4* src = reinterpret_cast<const float4*>(emb + i);
        const float4 a = src[0];
        const float4 b = src[1];
        uint2 o;
        o.x = enc4(a);
        o.y = enc4(b);
        reinterpret_cast<uint2*>(tbl)[i / 8] = o;
    }
}

// One wave per ACTIVE row (round-1 verified body: HW cvt_pk decode, 32-bit
// offsets, 1-deep prefetch — best measured at 93.0 us). The final divide by
// cnt_active is folded into each block's single atomicAdd to out[0]
// (out zeroed by prep), eliminating the finalize dispatch.
// NOTE (rounds 1-7): row_loss is pinned at ~94 us across 5 structural
// variants; FETCH 136 MB = 1.33x the 102 MB compulsory L2-fill floor at
// ~0.94 lines/cyc/XCD ~ the L2 fill service cap. Do not re-litigate.
__global__ __launch_bounds__(256) void row_loss_fp8(
    const float* __restrict__ emb,
    const uchar* __restrict__ tblb,
    const int* __restrict__ nbr,
    const int* __restrict__ nbrm,
    const int* __restrict__ neg,
    const int* __restrict__ list,
    const float* __restrict__ acc,
    float* __restrict__ out) {
    __shared__ float s_num[4];
    const int wave = threadIdx.x >> 6;
    const int lane = threadIdx.x & 63;
    const int g = lane >> 4;
    const int t = lane & 15;
    const uint lane_off = (uint)t * 16u;

    const int cnt_active = reinterpret_cast<const int*>(acc)[2];
    const int i = blockIdx.x * 4 + wave;
    float num = 0.f;

    if (i < cnt_active) {  // wave-uniform
        const int n = list[i];

        // own row fp32 (exact), elems 16t..16t+15
        const float4* erow = reinterpret_cast<const float4*>(emb + (size_t)n * kD);
        float own[16];
#pragma unroll
        for (int j = 0; j < 4; ++j) {
            const float4 f = erow[4 * t + j];
            own[4 * j + 0] = f.x * kOwnScale;
            own[4 * j + 1] = f.y * kOwnScale;
            own[4 * j + 2] = f.z * kOwnScale;
            own[4 * j + 3] = f.w * kOwnScale;
        }

        const int* nrow = nbr + (size_t)n * kPos;
        const int* mrow = nbrm + (size_t)n * kPos;
        const int* grow = neg + (size_t)n * kNeg;

        // preload all offsets + weights: keeps the slot loop branch-free and
        // lets the compiler software-pipeline the gathers.
        uint off[kSlots];  // 32-bit byte offsets into the 12.8 MB table
        float w[kPos / 4];
        float cnt = 0.f;
#pragma unroll
        for (int s = 0; s < kPos / 4; ++s) {
            off[s] = ((uint)nrow[s * 4 + g] << 8) + lane_off;
            const float mf = (float)mrow[s * 4 + g];
            w[s] = mf;
            cnt += mf;
        }
#pragma unroll
        for (int s = 0; s < kNeg / 4; ++s)
            off[kPos / 4 + s] = ((uint)grow[s * 4 + g] << 8) + lane_off;

        float pos_sum = 0.f, neg_sum = 0.f;
        // 1-deep explicit prefetch: next slot's 16B gather is in flight while
        // the current slot decodes/reduces.
        uint4 u = *reinterpret_cast<const uint4*>(tblb + off[0]);
#pragma unroll
        for (int s = 0; s < kSlots; ++s) {
            const uint4 uc = u;
            if (s + 1 < kSlots)
                u = *reinterpret_cast<const uint4*>(tblb + off[s + 1]);
            float d = 0.f;
            dq4(uc.x, own + 0, d);
            dq4(uc.y, own + 4, d);
            dq4(uc.z, own + 8, d);
            dq4(uc.w, own + 12, d);
            d += __shfl_xor(d, 8);
            d += __shfl_xor(d, 4);
            d += __shfl_xor(d, 2);
            d += __shfl_xor(d, 1);
            const float sg = 1.f / (1.f + __expf(-d));
            if (s < kPos / 4) {  // compile-time branch (fully unrolled)
                pos_sum += -__logf(sg + kEps) * w[s];
            } else {
                neg_sum += -__logf(1.f - sg + kEps);
            }
        }

        // combine the 4 groups (each group's 16 lanes hold identical values)
        pos_sum += __shfl_xor(pos_sum, 16);
        pos_sum += __shfl_xor(pos_sum, 32);
        neg_sum += __shfl_xor(neg_sum, 16);
        neg_sum += __shfl_xor(neg_sum, 32);
        cnt += __shfl_xor(cnt, 16);
        cnt += __shfl_xor(cnt, 32);

        if (cnt > 0.f) num = pos_sum / cnt + neg_sum / (float)kNeg;
        // cnt==0 -> NaN row in reference -> replaced by 0 -> contributes 0
    }

    if (lane == 0) s_num[wave] = num;
    __syncthreads();
    if (threadIdx.x == 0) {
        const float v = s_num[0] + s_num[1] + s_num[2] + s_num[3];
        // fold the final /cnt_active into the accumulation (out zeroed by prep)
        if (v != 0.f) atomicAdd(out, v / (float)cnt_active);
    }
}

// ---------- fp32 direct fallback (only if d_ws too small; UNCHANGED) ----------
__global__ __launch_bounds__(256) void row_loss_f32(
    const float* __restrict__ emb,
    const int* __restrict__ nbr,
    const int* __restrict__ nbrm,
    const int* __restrict__ neg,
    const int* __restrict__ rmask,
    float* __restrict__ acc) {
    __shared__ float s_num[4];
    __shared__ float s_den[4];
    const int wave = threadIdx.x >> 6;
    const int lane = threadIdx.x & 63;
    const int n = blockIdx.x * 4 + wave;
    const int g = lane >> 4;
    const int t = lane & 15;

    const float4* erow = reinterpret_cast<const float4*>(emb + (size_t)n * kD);
    float4 own4[4];
#pragma unroll
    for (int j = 0; j < 4; ++j) own4[j] = erow[j * 16 + t];

    const int* nrow = nbr + (size_t)n * kPos;
    const int* mrow = nbrm + (size_t)n * kPos;
    const int* grow = neg + (size_t)n * kNeg;

    float pos_sum = 0.f, neg_sum = 0.f, cnt = 0.f;
#pragma unroll
    for (int it = 0; it < kPos / 4; ++it) {
        const int idx = nrow[it * 4 + g];
        const float mf = (float)mrow[it * 4 + g];
        cnt += mf;
        const float4* brow = reinterpret_cast<const float4*>(emb + (size_t)idx * kD);
        float d = 0.f;
#pragma unroll
        for (int j = 0; j < 4; ++j) {
            const float4 b = brow[j * 16 + t];
            const float4 a = own4[j];
            d += a.x * b.x + a.y * b.y + a.z * b.z + a.w * b.w;
        }
        d += __shfl_xor(d, 8);
        d += __shfl_xor(d, 4);
        d += __shfl_xor(d, 2);
        d += __shfl_xor(d, 1);
        const float s = 1.f / (1.f + __expf(-d));
        pos_sum += -__logf(s + kEps) * mf;
    }
#pragma unroll
    for (int it = 0; it < kNeg / 4; ++it) {
        const int idx = grow[it * 4 + g];
        const float4* brow = reinterpret_cast<const float4*>(emb + (size_t)idx * kD);
        float d = 0.f;
#pragma unroll
        for (int j = 0; j < 4; ++j) {
            const float4 b = brow[j * 16 + t];
            const float4 a = own4[j];
            d += a.x * b.x + a.y * b.y + a.z * b.z + a.w * b.w;
        }
        d += __shfl_xor(d, 8);
        d += __shfl_xor(d, 4);
        d += __shfl_xor(d, 2);
        d += __shfl_xor(d, 1);
        const float s = 1.f / (1.f + __expf(-d));
        neg_sum += -__logf(1.f - s + kEps);
    }

    pos_sum += __shfl_xor(pos_sum, 16);
    pos_sum += __shfl_xor(pos_sum, 32);
    neg_sum += __shfl_xor(neg_sum, 16);
    neg_sum += __shfl_xor(neg_sum, 32);
    cnt += __shfl_xor(cnt, 16);
    cnt += __shfl_xor(cnt, 32);

    float num = 0.f;
    if (cnt > 0.f) num = pos_sum / cnt + neg_sum / (float)kNeg;
    const float rmf = (float)rmask[n];

    if (lane == 0) {
        s_num[wave] = num * rmf;
        s_den[wave] = rmf;
    }
    __syncthreads();
    if (threadIdx.x == 0) {
        atomicAdd(&acc[0], s_num[0] + s_num[1] + s_num[2] + s_num[3]);
        atomicAdd(&acc[1], s_den[0] + s_den[1] + s_den[2] + s_den[3]);
    }
}

__global__ void finalize_f32(const float* __restrict__ acc, float* __restrict__ out) {
    out[0] = acc[0] / acc[1];
}
}  // namespace

extern "C" void kernel_launch(void* const* d_in, const int* in_sizes, int n_in,
                              void* d_out, int out_size, void* d_ws, size_t ws_size,
                              hipStream_t stream) {
    const float* emb = (const float*)d_in[0];
    const int* nbr = (const int*)d_in[1];
    const int* nbrm = (const int*)d_in[2];
    const int* neg = (const int*)d_in[3];
    const int* rmask = (const int*)d_in[4];
    float* acc = (float*)d_ws;  // [0]=num, [1]=den, [2]=active count

    const size_t tbl_bytes = (size_t)kN * kD;  // 12.8 MB
    const size_t list_bytes = (size_t)kN * sizeof(int);
    if (ws_size >= 256 + tbl_bytes + list_bytes) {
        uint* tbl = (uint*)((char*)d_ws + 256);
        int* list = (int*)((char*)d_ws + 256 + tbl_bytes);
        hipMemsetAsync(acc, 0, 4 * sizeof(float), stream);
        prep_kernel<<<kCompactBlocks + kConvertBlocks, 256, 0, stream>>>(
            emb, tbl, rmask, list, acc, (float*)d_out);
        row_loss_fp8<<<(kN + 3) / 4, 256, 0, stream>>>(emb, (const uchar*)tbl, nbr,
                                                       nbrm, neg, list, acc,
                                                       (float*)d_out);
    } else {
        hipMemsetAsync(acc, 0, 2 * sizeof(float), stream);
        row_loss_f32<<<kN / 4, 256, 0, stream>>>(emb, nbr, nbrm, neg, rmask, acc);
        finalize_f32<<<1, 1, 0, stream>>>(acc, (float*)d_out);
    }
}